// Round 7
// baseline (433.328 us; speedup 1.0000x reference)
//
#include <hip/hip_runtime.h>

#define EMB 300
#define EMB4 75            // 300/4
#define NBLK 1024
#define NTHR 256
#define NWAVES (NBLK * NTHR / 64)   // 4096

struct Ctrl { int next; int arrive; int release; int pad; };

// One persistent kernel:
//   phase 0: boundary sweep of sorted segment_ids -> bounds[]
//   phase 1: dot2[v] = (emb[v]·W[:300], emb[v]·W[300:]) — dynamic row-groups
//   barrier: software grid barrier (all 1024 blocks resident by launch_bounds)
//   phase 2: per-pair gather + mean + sigmoid
__global__ __launch_bounds__(NTHR, 4)
void mega_kernel(const float* __restrict__ emb,
                 const float* __restrict__ W,
                 const int* __restrict__ token_ids,
                 const int* __restrict__ segment_ids,
                 const float* __restrict__ bptr,
                 float2* __restrict__ dot2,
                 int* __restrict__ bounds,
                 Ctrl* __restrict__ ctrl,
                 float* __restrict__ out,
                 int vocab, int T, int nseg, int pairs) {
    const int gtid = blockIdx.x * NTHR + threadIdx.x;
    const int lane = threadIdx.x & 63;
    const int w    = gtid >> 6;

    // ---- phase 0: segment boundaries (2.6 MB stream, ~3 elems/thread) ----
    for (int j = gtid; j < T; j += NBLK * NTHR) {
        int cur = segment_ids[j];
        if (j == 0) {
            for (int s = 0; s <= cur; ++s) bounds[s] = 0;
        } else {
            int prev = segment_ids[j - 1];
            for (int s = prev + 1; s <= cur; ++s) bounds[s] = j;
        }
        if (j == T - 1) {
            for (int s = cur + 1; s <= nseg; ++s) bounds[s] = T;
        }
    }

    // ---- phase 1: dot products, 4 rows per wave-iteration ----
    const float4* W4 = (const float4*)W;   // 600 floats = 150 float4
    const int l  = lane & 15;              // lane within 16-lane group
    const int gq = lane >> 4;              // which of the 4 rows

    float4 wa[5], wb[5];
    #pragma unroll
    for (int it = 0; it < 5; ++it) {
        int k = l + it * 16;
        wa[it] = (k < EMB4) ? W4[k]        : make_float4(0.f, 0.f, 0.f, 0.f);
        wb[it] = (k < EMB4) ? W4[EMB4 + k] : make_float4(0.f, 0.f, 0.f, 0.f);
    }

    const int ngroups = (vocab + 3) >> 2;
    int g = w;  // first group static; rest via work-stealing
    while (g < ngroups) {
        int row = g * 4 + gq;
        bool active = (row < vocab);
        const float4* e4 = (const float4*)(emb + (size_t)(active ? row : 0) * EMB);

        float a = 0.f, b = 0.f;
        #pragma unroll
        for (int it = 0; it < 5; ++it) {
            int k = l + it * 16;
            if (active && k < EMB4) {
                float4 v = e4[k];
                a += v.x * wa[it].x + v.y * wa[it].y + v.z * wa[it].z + v.w * wa[it].w;
                b += v.x * wb[it].x + v.y * wb[it].y + v.z * wb[it].z + v.w * wb[it].w;
            }
        }
        // fetch next group while the reduce runs
        int gn = 0;
        if (lane == 0) gn = NWAVES + atomicAdd(&ctrl->next, 1);
        #pragma unroll
        for (int m = 8; m > 0; m >>= 1) {
            a += __shfl_xor(a, m, 64);
            b += __shfl_xor(b, m, 64);
        }
        if (active && l == 0) dot2[row] = make_float2(a, b);
        g = __shfl(gn, 0, 64);
    }

    // ---- grid barrier (all NBLK blocks resident: launch_bounds caps VGPR<=128
    //      -> 4 blocks/CU x 256 CUs = 1024) ----
    __syncthreads();
    if (threadIdx.x == 0) {
        __threadfence();  // make this block's dot2/bounds writes visible
        int prev = atomicAdd(&ctrl->arrive, 1);   // device scope
        if (prev == NBLK - 1) {
            __hip_atomic_store(&ctrl->release, 1, __ATOMIC_RELEASE,
                               __HIP_MEMORY_SCOPE_AGENT);
        } else {
            while (__hip_atomic_load(&ctrl->release, __ATOMIC_ACQUIRE,
                                     __HIP_MEMORY_SCOPE_AGENT) == 0)
                __builtin_amdgcn_s_sleep(2);
        }
        __threadfence();
    }
    __syncthreads();

    // ---- phase 2: one wave per pair, 4 pairs per wave ----
    float bias = bptr[0];
    for (int p = w; p < pairs; p += NWAVES) {
        int i0 = bounds[2 * p];
        int i1 = bounds[2 * p + 1];
        int i2 = bounds[2 * p + 2];

        float sA = 0.f, sB = 0.f;
        for (int j = i0 + lane; j < i2; j += 64) {
            float2 d = dot2[token_ids[j]];
            if (j < i1) sA += d.x; else sB += d.y;
        }
        #pragma unroll
        for (int off = 32; off > 0; off >>= 1) {
            sA += __shfl_down(sA, off, 64);
            sB += __shfl_down(sB, off, 64);
        }
        if (lane == 0) {
            float m0 = sA / fmaxf((float)(i1 - i0), 1.0f);
            float m1 = sB / fmaxf((float)(i2 - i1), 1.0f);
            float logit = m0 + m1 + bias;
            out[p] = 1.0f / (1.0f + expf(-logit));
        }
    }
}

extern "C" void kernel_launch(void* const* d_in, const int* in_sizes, int n_in,
                              void* d_out, int out_size, void* d_ws, size_t ws_size,
                              hipStream_t stream) {
    const float* emb         = (const float*)d_in[0];
    const float* W           = (const float*)d_in[1];
    const float* b           = (const float*)d_in[2];
    const int*   token_ids   = (const int*)d_in[3];
    const int*   segment_ids = (const int*)d_in[4];

    const int T     = in_sizes[3];
    const int vocab = in_sizes[0] / EMB;
    const int pairs = out_size;
    const int nseg  = pairs * 2;

    Ctrl*   ctrl   = (Ctrl*)d_ws;
    float2* dot2   = (float2*)((char*)d_ws + sizeof(Ctrl));  // 100000*8B
    int*    bounds = (int*)(dot2 + vocab);                   // 32769*4B

    // zero the work-steal counter + barrier state each call
    hipMemsetAsync(ctrl, 0, sizeof(Ctrl), stream);

    mega_kernel<<<NBLK, NTHR, 0, stream>>>(
        emb, W, token_ids, segment_ids, b,
        dot2, bounds, ctrl, (float*)d_out,
        vocab, T, nseg, pairs);
}

// Round 8
// 432.901 us; speedup vs baseline: 1.0010x; 1.0010x over previous
//
#include <hip/hip_runtime.h>

#define EMB 300
#define EMB4 75            // 300/4
#define NBLK 1024
#define NTHR 256
#define NWAVES (NBLK * NTHR / 64)   // 4096

struct Ctrl { int next; int arrive; int release; int pad; };

// One persistent kernel:
//   phase 0: boundary sweep of sorted segment_ids -> bounds[]
//   phase 1: dot2[v] = (emb[v]·W[:300], emb[v]·W[300:]) — dynamic row-groups
//   barrier: software grid barrier (all 1024 blocks resident by launch_bounds)
//   phase 2: per-pair gather + mean + sigmoid
__global__ __launch_bounds__(NTHR, 4)
void mega_kernel(const float* __restrict__ emb,
                 const float* __restrict__ W,
                 const int* __restrict__ token_ids,
                 const int* __restrict__ segment_ids,
                 const float* __restrict__ bptr,
                 float2* __restrict__ dot2,
                 int* __restrict__ bounds,
                 Ctrl* __restrict__ ctrl,
                 float* __restrict__ out,
                 int vocab, int T, int nseg, int pairs) {
    const int gtid = blockIdx.x * NTHR + threadIdx.x;
    const int lane = threadIdx.x & 63;
    const int w    = gtid >> 6;

    // ---- phase 0: segment boundaries (2.6 MB stream, ~3 elems/thread) ----
    for (int j = gtid; j < T; j += NBLK * NTHR) {
        int cur = segment_ids[j];
        if (j == 0) {
            for (int s = 0; s <= cur; ++s) bounds[s] = 0;
        } else {
            int prev = segment_ids[j - 1];
            for (int s = prev + 1; s <= cur; ++s) bounds[s] = j;
        }
        if (j == T - 1) {
            for (int s = cur + 1; s <= nseg; ++s) bounds[s] = T;
        }
    }

    // ---- phase 1: dot products, 4 rows per wave-iteration ----
    const float4* W4 = (const float4*)W;   // 600 floats = 150 float4
    const int l  = lane & 15;              // lane within 16-lane group
    const int gq = lane >> 4;              // which of the 4 rows

    float4 wa[5], wb[5];
    #pragma unroll
    for (int it = 0; it < 5; ++it) {
        int k = l + it * 16;
        wa[it] = (k < EMB4) ? W4[k]        : make_float4(0.f, 0.f, 0.f, 0.f);
        wb[it] = (k < EMB4) ? W4[EMB4 + k] : make_float4(0.f, 0.f, 0.f, 0.f);
    }

    const int ngroups = (vocab + 3) >> 2;
    int g = w;  // first group static; rest via work-stealing
    while (g < ngroups) {
        int row = g * 4 + gq;
        bool active = (row < vocab);
        const float4* e4 = (const float4*)(emb + (size_t)(active ? row : 0) * EMB);

        float a = 0.f, b = 0.f;
        #pragma unroll
        for (int it = 0; it < 5; ++it) {
            int k = l + it * 16;
            if (active && k < EMB4) {
                float4 v = e4[k];
                a += v.x * wa[it].x + v.y * wa[it].y + v.z * wa[it].z + v.w * wa[it].w;
                b += v.x * wb[it].x + v.y * wb[it].y + v.z * wb[it].z + v.w * wb[it].w;
            }
        }
        // fetch next group while the reduce runs
        int gn = 0;
        if (lane == 0) gn = NWAVES + atomicAdd(&ctrl->next, 1);
        #pragma unroll
        for (int m = 8; m > 0; m >>= 1) {
            a += __shfl_xor(a, m, 64);
            b += __shfl_xor(b, m, 64);
        }
        if (active && l == 0) dot2[row] = make_float2(a, b);
        g = __shfl(gn, 0, 64);
    }

    // ---- grid barrier (all NBLK blocks resident: launch_bounds caps VGPR<=128
    //      -> 4 blocks/CU x 256 CUs = 1024) ----
    __syncthreads();
    if (threadIdx.x == 0) {
        __threadfence();  // make this block's dot2/bounds writes visible
        int prev = atomicAdd(&ctrl->arrive, 1);   // device scope
        if (prev == NBLK - 1) {
            __hip_atomic_store(&ctrl->release, 1, __ATOMIC_RELEASE,
                               __HIP_MEMORY_SCOPE_AGENT);
        } else {
            while (__hip_atomic_load(&ctrl->release, __ATOMIC_ACQUIRE,
                                     __HIP_MEMORY_SCOPE_AGENT) == 0)
                __builtin_amdgcn_s_sleep(2);
        }
        __threadfence();
    }
    __syncthreads();

    // ---- phase 2: one wave per pair, 4 pairs per wave ----
    float bias = bptr[0];
    for (int p = w; p < pairs; p += NWAVES) {
        int i0 = bounds[2 * p];
        int i1 = bounds[2 * p + 1];
        int i2 = bounds[2 * p + 2];

        float sA = 0.f, sB = 0.f;
        for (int j = i0 + lane; j < i2; j += 64) {
            float2 d = dot2[token_ids[j]];
            if (j < i1) sA += d.x; else sB += d.y;
        }
        #pragma unroll
        for (int off = 32; off > 0; off >>= 1) {
            sA += __shfl_down(sA, off, 64);
            sB += __shfl_down(sB, off, 64);
        }
        if (lane == 0) {
            float m0 = sA / fmaxf((float)(i1 - i0), 1.0f);
            float m1 = sB / fmaxf((float)(i2 - i1), 1.0f);
            float logit = m0 + m1 + bias;
            out[p] = 1.0f / (1.0f + expf(-logit));
        }
    }
}

extern "C" void kernel_launch(void* const* d_in, const int* in_sizes, int n_in,
                              void* d_out, int out_size, void* d_ws, size_t ws_size,
                              hipStream_t stream) {
    const float* emb         = (const float*)d_in[0];
    const float* W           = (const float*)d_in[1];
    const float* b           = (const float*)d_in[2];
    const int*   token_ids   = (const int*)d_in[3];
    const int*   segment_ids = (const int*)d_in[4];

    const int T     = in_sizes[3];
    const int vocab = in_sizes[0] / EMB;
    const int pairs = out_size;
    const int nseg  = pairs * 2;

    Ctrl*   ctrl   = (Ctrl*)d_ws;
    float2* dot2   = (float2*)((char*)d_ws + sizeof(Ctrl));  // 100000*8B
    int*    bounds = (int*)(dot2 + vocab);                   // 32769*4B

    // zero the work-steal counter + barrier state each call
    hipMemsetAsync(ctrl, 0, sizeof(Ctrl), stream);

    mega_kernel<<<NBLK, NTHR, 0, stream>>>(
        emb, W, token_ids, segment_ids, b,
        dot2, bounds, ctrl, (float*)d_out,
        vocab, T, nseg, pairs);
}

// Round 9
// 33.511 us; speedup vs baseline: 12.9309x; 12.9181x over previous
//
#include <hip/hip_runtime.h>

#define EMB 300
#define EMB4 75  // 300/4

// Fused kernel 1:
//   blocks [0, blocks_bnd): boundary sweep over sorted segment_ids:
//       bounds[s] = first token index with segment_ids >= s, s in [0, nseg]
//   blocks [blocks_bnd, gridDim): dot2[v] = (emb[v]·W[:300], emb[v]·W[300:])
//       grid-stride over 4-row groups; 16-lane group per row; 5 float4
//       loads in flight per lane-group; W held in registers.
// 2048 dot blocks = 32 waves/CU -> enough MLP to saturate the read stream.
__global__ void fused1_kernel(const float* __restrict__ emb,
                              const float* __restrict__ W,
                              const int* __restrict__ segment_ids,
                              float2* __restrict__ dot2,
                              int* __restrict__ bounds,
                              int vocab, int T, int nseg, int blocks_bnd) {
    if ((int)blockIdx.x < blocks_bnd) {
        // ---- boundary pass: one streaming sweep of segment_ids ----
        int tid    = blockIdx.x * blockDim.x + threadIdx.x;
        int stride = blocks_bnd * blockDim.x;
        for (int j = tid; j < T; j += stride) {
            int cur = segment_ids[j];
            if (j == 0) {
                for (int s = 0; s <= cur; ++s) bounds[s] = 0;
            } else {
                int prev = segment_ids[j - 1];
                for (int s = prev + 1; s <= cur; ++s) bounds[s] = j;
            }
            if (j == T - 1) {
                for (int s = cur + 1; s <= nseg; ++s) bounds[s] = T;
            }
        }
    } else {
        // ---- dot pass ----
        const float4* W4 = (const float4*)W;  // 600 floats = 150 float4
        int wave   = ((blockIdx.x - blocks_bnd) * blockDim.x + threadIdx.x) >> 6;
        int nwaves = ((gridDim.x - blocks_bnd) * blockDim.x) >> 6;
        int lane   = threadIdx.x & 63;
        int l      = lane & 15;   // lane within 16-lane group
        int gq     = lane >> 4;   // which of the wave's 4 rows

        float4 wa[5], wb[5];
        #pragma unroll
        for (int it = 0; it < 5; ++it) {
            int k = l + it * 16;
            wa[it] = (k < EMB4) ? W4[k]        : make_float4(0.f, 0.f, 0.f, 0.f);
            wb[it] = (k < EMB4) ? W4[EMB4 + k] : make_float4(0.f, 0.f, 0.f, 0.f);
        }

        int ngroups = (vocab + 3) >> 2;  // 4-row groups
        for (int rg = wave; rg < ngroups; rg += nwaves) {
            int row = rg * 4 + gq;
            bool active = (row < vocab);
            const float4* e4 =
                (const float4*)(emb + (size_t)(active ? row : 0) * EMB);

            float a = 0.f, b = 0.f;
            #pragma unroll
            for (int it = 0; it < 5; ++it) {
                int k = l + it * 16;
                if (active && k < EMB4) {
                    float4 v = e4[k];
                    a += v.x * wa[it].x + v.y * wa[it].y +
                         v.z * wa[it].z + v.w * wa[it].w;
                    b += v.x * wb[it].x + v.y * wb[it].y +
                         v.z * wb[it].z + v.w * wb[it].w;
                }
            }
            #pragma unroll
            for (int m = 8; m > 0; m >>= 1) {
                a += __shfl_xor(a, m, 64);
                b += __shfl_xor(b, m, 64);
            }
            if (active && l == 0) dot2[row] = make_float2(a, b);
        }
    }
}

// Kernel 2: one wave per output pair; lanes 0-31 gather segment A,
// lanes 32-63 gather segment B concurrently; single xor-reduce tree.
__global__ void pair_kernel(const int* __restrict__ token_ids,
                            const int* __restrict__ bounds,
                            const float2* __restrict__ dot2,
                            const float* __restrict__ bptr,
                            float* __restrict__ out,
                            int pairs) {
    int wave = (blockIdx.x * blockDim.x + threadIdx.x) >> 6;
    int lane = threadIdx.x & 63;
    if (wave >= pairs) return;

    int i0 = bounds[2 * wave];
    int i1 = bounds[2 * wave + 1];
    int i2 = bounds[2 * wave + 2];

    bool hi  = (lane >= 32);
    int  beg = hi ? i1 : i0;
    int  end = hi ? i2 : i1;

    float s = 0.f;
    for (int j = beg + (lane & 31); j < end; j += 32) {
        float2 d = dot2[token_ids[j]];
        s += hi ? d.y : d.x;
    }
    #pragma unroll
    for (int m = 16; m > 0; m >>= 1) s += __shfl_xor(s, m, 64);
    float other = __shfl_xor(s, 32, 64);  // lane 0 now sees lane 32's sum

    if (lane == 0) {
        float m0 = s     / fmaxf((float)(i1 - i0), 1.0f);
        float m1 = other / fmaxf((float)(i2 - i1), 1.0f);
        float logit = m0 + m1 + bptr[0];
        out[wave] = 1.0f / (1.0f + expf(-logit));
    }
}

extern "C" void kernel_launch(void* const* d_in, const int* in_sizes, int n_in,
                              void* d_out, int out_size, void* d_ws, size_t ws_size,
                              hipStream_t stream) {
    const float* emb         = (const float*)d_in[0];
    const float* W           = (const float*)d_in[1];
    const float* b           = (const float*)d_in[2];
    const int*   token_ids   = (const int*)d_in[3];
    const int*   segment_ids = (const int*)d_in[4];

    const int T     = in_sizes[3];
    const int vocab = in_sizes[0] / EMB;
    const int pairs = out_size;
    const int nseg  = pairs * 2;

    float2* dot2   = (float2*)d_ws;          // 100000 * 8B = 800 KB
    int*    bounds = (int*)(dot2 + vocab);   // (nseg+1) * 4B

    // bounds blocks first so pair inputs are ready earliest; then 2048 dot
    // blocks -> 8 blocks/CU = 32 waves/CU of pure streaming.
    int blocks_bnd = 256;
    int blocks_dot = 2048;
    fused1_kernel<<<blocks_bnd + blocks_dot, 256, 0, stream>>>(
        emb, W, segment_ids, dot2, bounds, vocab, T, nseg, blocks_bnd);

    // one wave per pair, 4 waves per block.
    pair_kernel<<<(pairs + 3) / 4, 256, 0, stream>>>(
        token_ids, bounds, dot2, b, (float*)d_out, pairs);
}